// Round 5
// baseline (122.394 us; speedup 1.0000x reference)
//
#include <hip/hip_runtime.h>

// out[n, mu, mup] = sum_{(m1,m2)∈T(mu)} sum_{(m1p,m2p)∈T(mup)}
//     mult[p*61+q] * X1[n,m1,m1p] * X2[n,m2,m2p],   T(mu)={m1+m2==mu+4}
// p,q = mu-major pair enumeration (61 pairs), weight index t = p*61+q.
//
// R5: R3/R4 kernel ~30us, LDS-pipe bound: [c][n] layout forced 18 scalar
// ds_read_b32 per pair (6.4k cyc/block) + runtime-bound m1 loop serialized
// the 61-weight s_loads. Changes:
//  - LDS layout [n][9 rows x 12-float pitch] (n-pitch 108 fl = 432 B, 16B
//    aligned): row read = 2x ds_read_b128 + 1x b32 (~30 cyc vs 52). Lane
//    bank stride 12 mod 32 -> each 8-lane group covers all 32 banks ->
//    conflict-free.
//  - m1 loop fully unrolled with wave-uniform scalar guard (mu from
//    readfirstlane) -> 9 static bodies, weight s_loads batchable/hoistable.
//  - output staged back through x1s rows via b128 writes, coalesced stores.

namespace {

// q-enumeration tables (mup-major, m1p ascending) — compile-time
struct QTab {
  int m1p[61];
  int m2p[61];
  int mup[61];
  constexpr QTab() : m1p{}, m2p{}, mup{} {
    int idx = 0;
    for (int mu = 0; mu < 9; ++mu)
      for (int a = 0; a < 9; ++a) {
        int b = mu + 4 - a;
        if (b >= 0 && b < 9) {
          m1p[idx] = a; m2p[idx] = b; mup[idx] = mu; ++idx;
        }
      }
  }
};
constexpr QTab QT{};

}  // namespace

// pairs per mu: [5,6,7,8,9,8,7,6,5]; prefix = first pair index of each mu
__constant__ __device__ int kPrefix[9] = {0, 5, 11, 18, 26, 35, 43, 50, 56};

#define NB 64            // n per block
#define NT 576           // threads = 9 waves (wave = mu, lane = n-local)
#define RP 12            // floats per row in LDS (9 used + 3 pad)
#define NP 108           // floats per n in LDS (9 rows x RP); 432 B, 16B-aligned
#define ELEMS (NB * 81)  // 5184 floats per array per block

__global__ __launch_bounds__(NT)
void wigner_combine_kernel(const float* __restrict__ X1,
                           const float* __restrict__ X2,
                           const float* __restrict__ mult,
                           float* __restrict__ out, int N) {
  __shared__ __align__(16) float x1s[NB * NP];  // 27648 B
  __shared__ __align__(16) float x2s[NB * NP];  // 27648 B

  const int t = threadIdx.x;
  const int base = blockIdx.x * ELEMS;
  const int total = N * 81;

  // ---- stage: coalesced global loads, transposed writes into [n][row] ----
#pragma unroll
  for (int j = 0; j < 9; ++j) {
    const int e = t + j * NT;      // 0..5183
    const int n = e / 81;          // magic-div
    const int c = e - n * 81;
    const int m = c / 9;
    const int jj = c - m * 9;
    const int ge = base + e;
    float v1 = 0.0f, v2 = 0.0f;
    if (ge < total) { v1 = X1[ge]; v2 = X2[ge]; }
    const int a = n * NP + m * RP + jj;
    x1s[a] = v1;
    x2s[a] = v2;
  }
  __syncthreads();

  // ---- compute: wave = mu, lane = local n ----
  const int mu = __builtin_amdgcn_readfirstlane(t >> 6);  // wave-uniform
  const int lane = t & 63;
  const int m1lo = (mu - 4 > 0) ? mu - 4 : 0;
  const int pbase = kPrefix[mu];

  const float* __restrict__ lx1 = x1s + lane * NP;
  const float* __restrict__ lx2 = x2s + lane * NP;

  float acc[9];
#pragma unroll
  for (int j = 0; j < 9; ++j) acc[j] = 0.0f;

#pragma unroll
  for (int m1 = 0; m1 < 9; ++m1) {
    const int m2 = mu + 4 - m1;      // scalar
    if (m2 < 0 || m2 > 8) continue;  // uniform scalar branch
    const int p = pbase + (m1 - m1lo);
    const float* __restrict__ w = mult + p * 61;  // SGPR base -> s_loads

    const float* r1 = lx1 + m1 * RP;  // 16B-aligned
    const float* r2 = lx2 + m2 * RP;
    const float4 a0 = ((const float4*)r1)[0];
    const float4 a1 = ((const float4*)r1)[1];
    const float  a2 = r1[8];
    const float4 b0 = ((const float4*)r2)[0];
    const float4 b1 = ((const float4*)r2)[1];
    const float  b2 = r2[8];
    const float x1r[9] = {a0.x, a0.y, a0.z, a0.w, a1.x, a1.y, a1.z, a1.w, a2};
    const float x2r[9] = {b0.x, b0.y, b0.z, b0.w, b1.x, b1.y, b1.z, b1.w, b2};

#pragma unroll
    for (int q = 0; q < 61; ++q) {
      acc[QT.mup[q]] = fmaf(w[q], x1r[QT.m1p[q]] * x2r[QT.m2p[q]],
                            acc[QT.mup[q]]);
    }
  }

  // ---- result back through x1s (row mu of each n), coalesced stores ----
  __syncthreads();
  float* orow = x1s + lane * NP + mu * RP;
  ((float4*)orow)[0] = make_float4(acc[0], acc[1], acc[2], acc[3]);
  ((float4*)orow)[1] = make_float4(acc[4], acc[5], acc[6], acc[7]);
  orow[8] = acc[8];
  __syncthreads();

#pragma unroll
  for (int j = 0; j < 9; ++j) {
    const int e = t + j * NT;
    const int n = e / 81;
    const int c = e - n * 81;
    const int m = c / 9;
    const int jj = c - m * 9;
    const int ge = base + e;
    if (ge < total) out[ge] = x1s[n * NP + m * RP + jj];
  }
}

extern "C" void kernel_launch(void* const* d_in, const int* in_sizes, int n_in,
                              void* d_out, int out_size, void* d_ws, size_t ws_size,
                              hipStream_t stream) {
  const float* X1 = (const float*)d_in[0];
  const float* X2 = (const float*)d_in[1];
  const float* mult = (const float*)d_in[6];
  float* out = (float*)d_out;

  const int N = in_sizes[0] / 81;
  const int blocks = (N + NB - 1) / NB;
  wigner_combine_kernel<<<blocks, NT, 0, stream>>>(X1, X2, mult, out, N);
}